// Round 18
// baseline (2050.096 us; speedup 1.0000x reference)
//
#include <hip/hip_runtime.h>
#include <hip/hip_fp16.h>
#include <cstdint>
#include <cstddef>

#define EPSF 2.220446049250313e-16f

// Sizes (fixed by the problem)
#define Bn   64
#define TP2n 1024
#define Tn   1023
#define Hn   256
#define H7n  1792
#define Kn   128
#define NEn  131

typedef _Float16 f16x2 __attribute__((ext_vector_type(2)));
typedef unsigned uintx4 __attribute__((ext_vector_type(4)));

__device__ __forceinline__ f16x2 u2h(unsigned u) { return __builtin_bit_cast(f16x2, u); }
__device__ __forceinline__ f16x2 f2h(float f)    { return __builtin_bit_cast(f16x2, f); }

// 4-way signed-byte dot product with int32 accumulate (v_dot4_i32_i8).
__device__ __forceinline__ int sdot4f(unsigned a, unsigned b, int c) {
#if __has_builtin(__builtin_amdgcn_sdot4)
  return __builtin_amdgcn_sdot4((int)a, (int)b, c, false);
#else
  int r = c;
#pragma unroll
  for (int i = 0; i < 4; ++i) {
    int av = ((int)(a << (24 - 8 * i))) >> 24;
    int bv = ((int)(b << (24 - 8 * i))) >> 24;
    r += av * bv;
  }
  return r;
#endif
}

__device__ __forceinline__ float sigmf(float x) { return 1.f / (1.f + __expf(-x)); }

__device__ __forceinline__ float tanhfast(float x) {
  float t = __expf(2.f * fabsf(x));        // inf-safe: t=inf -> r=1
  float r = 1.f - 2.f / (t + 1.f);
  return copysignf(r, x);
}

__device__ __forceinline__ float softplusf(float x) {
  return fmaxf(x, 0.f) + log1pf(__expf(-fabsf(x)));
}

// Row permutation: r' = role*448 + g*64 + u  <->  orig r = g*256 + 64*role + u.
// Role r' block then owns ALL 7 gates of units [64*role, 64*role+64):
// Phase B is block-local; only h (256 int8) crosses blocks.
__device__ __host__ __forceinline__ int orig_row(int rp) {
  int role = rp / 448, i = rp % 448;
  return (i >> 6) * 256 + 64 * role + (i & 63);
}

// ---------------------------------------------------------------------------
// EWp[e][r'] = b[orig(r')] + sum_k Emb[e][k] * W[orig(r')][k]   (k<256)
// Wave-per-row: lane l reads W[r][4l..4l+3] (coalesced 1KB/row) + shuffle
// reduce.
__global__ __launch_bounds__(256) void k_ew(
    const float* __restrict__ Emb, const float* __restrict__ W,
    const float* __restrict__ bvec, float* __restrict__ EW) {
  const int e = blockIdx.x;      // 0..130
  const int chunk = blockIdx.y;  // 0..15
  const int tid = threadIdx.x;
  __shared__ float es[Hn];
  es[tid] = Emb[e * Hn + tid];
  __syncthreads();
  const int wv = tid >> 6, l = tid & 63;
  float4 ev = reinterpret_cast<const float4*>(es)[l];
  for (int i = 0; i < 28; ++i) {
    int rp = chunk * 112 + wv * 28 + i;
    int r = orig_row(rp);
    float4 wf = *reinterpret_cast<const float4*>(W + (size_t)r * 512 + 4 * l);
    float s = wf.x * ev.x + wf.y * ev.y + wf.z * ev.z + wf.w * ev.w;
#pragma unroll
    for (int off = 32; off; off >>= 1) s += __shfl_down(s, off);
    if (l == 0) EW[e * H7n + rp] = bvec[r] + s;
  }
}

// ---------------------------------------------------------------------------
// Quantize recurrent weights to int8 with per-row scale, PERMUTED rows.
// Dword j of row r' = bytes (k=4j..4j+3), natural order (matches sdot4 with
// h packed unit-major 4/dword). sc[r'] = max/127^2 (weight scale x h scale).
__global__ __launch_bounds__(64) void k_wq8(const float* __restrict__ W,
                                            unsigned* __restrict__ wq,
                                            float* __restrict__ sc) {
  const int rp = blockIdx.x;          // 0..1791 (permuted index)
  const int r  = orig_row(rp);
  const int j  = threadIdx.x;         // 0..63
  const float* wr = W + (size_t)r * 512 + 256;
  float4 wv = *reinterpret_cast<const float4*>(wr + 4 * j);
  float m = fmaxf(fmaxf(fabsf(wv.x), fabsf(wv.y)),
                  fmaxf(fabsf(wv.z), fabsf(wv.w)));
#pragma unroll
  for (int off = 32; off; off >>= 1) m = fmaxf(m, __shfl_xor(m, off));
  float inv = (m > 0.f) ? 127.f / m : 0.f;
  float v[4] = {wv.x, wv.y, wv.z, wv.w};
  unsigned d = 0;
#pragma unroll
  for (int q = 0; q < 4; ++q) {
    float s = fminf(fmaxf(v[q] * inv, -127.f), 127.f);
    unsigned byte = (unsigned)((int)rintf(s)) & 255u;
    d |= byte << (8 * q);
  }
  wq[(size_t)rp * 64 + j] = d;
  if (j == 0) sc[rp] = m / (127.f * 127.f);
}

// ---------------------------------------------------------------------------
// Quantize Wl to int8, TRANSPOSED for k_samp's LDS layout.
__global__ __launch_bounds__(64) void k_wlq(const float* __restrict__ Wl,
                                            unsigned* __restrict__ wlq,
                                            float* __restrict__ scl) {
  const int r = blockIdx.x;           // 0..127
  const int j = threadIdx.x;          // 0..63
  const float* row = Wl + (size_t)r * Hn;
  float4 v = reinterpret_cast<const float4*>(row)[j];
  float m = fmaxf(fmaxf(fabsf(v.x), fabsf(v.y)),
                  fmaxf(fabsf(v.z), fabsf(v.w)));
#pragma unroll
  for (int off = 32; off; off >>= 1) m = fmaxf(m, __shfl_xor(m, off));
  float inv = (m > 0.f) ? 127.f / m : 0.f;
  float vv[4] = {v.x, v.y, v.z, v.w};
  unsigned d = 0;
#pragma unroll
  for (int qi = 0; qi < 4; ++qi) {
    unsigned byte = (unsigned)((int)rintf(
        fminf(fmaxf(vv[qi] * inv, -127.f), 127.f))) & 255u;
    d |= byte << (8 * qi);
  }
  wlq[(((size_t)(j >> 2)) * 128 + r) * 4 + (j & 3)] = d;
  if (j == 0) scl[r] = m / (127.f * 127.f);
}

// ---------------------------------------------------------------------------
// Init accumulators and the h-exchange buffer. hx dwords get lsb=1: first
// expected tag is 0, so poison / stale replay data can never false-positive.
__global__ void k_init(float* __restrict__ acc, unsigned* __restrict__ hx) {
  int i = threadIdx.x;  // 1024 threads
  if (i < 192) acc[i] = 0.f;  // lam_acc[64], mask_acc[64], loglik_sum[64]
  for (int k = i; k < Bn * 128; k += 1024) hx[k] = 1u;
}

// ---------------------------------------------------------------------------
// Sequential CT-LSTM scan, 4 blocks/batch, 448 threads, 1 permuted row each
// (round-14/17 structure; 1.85us/step measured, dominated by the
// publish->MALL->poll round trip). This round overlaps the overlappable:
//  - Phase A is split by column locality: the 4 LOCAL i-groups (own 64
//    units) depend only on own-block h -> computed as `aloc` in the exchange
//    section, under the poll RT, gated by an LDS flag (workgroup-scope
//    release by wave 0 after writing h_local; all waves acquire-spin —
//    intra-block only, deadlock-free). Critical-path Phase A drops 64->48
//    sdot4. Integer partials sum identically -> bit-identical results.
//  - s_setprio(1) around wave 0's gate math (wave role-split exists:
//    wave 0 critical, waves 2-6 parked at the flag).
__global__ __launch_bounds__(448) void k_scan(
    const int* __restrict__ event, const float* __restrict__ dtime,
    const float* __restrict__ EW, const unsigned* __restrict__ wq,
    const float* __restrict__ sc, unsigned* __restrict__ hx,
    uint2* __restrict__ state) {
  const int x = blockIdx.x;
  // co-locate a batch's 4 blocks on one XCD (assumed xcd = blockIdx % 8);
  // correctness does not depend on this mapping.
  const int xcd = x & 7, q = x >> 3;
  const int b = xcd * 8 + (q >> 2);
  const int role = q & 3;
  const int tid = threadIdx.x;
  const int row = role * 448 + tid;     // permuted row index

  __shared__ float    zbuf[448];        // this block's z slice (local!)
  __shared__ uintx4   hds8q[16];        // 256 int8 h, unit-major 4/dword
  __shared__ int      ev_s[TP2n];
  __shared__ float    dt_s[TP2n];
  __shared__ int      hflag;            // h_local-ready flag (monotonic)
  unsigned* hds8 = reinterpret_cast<unsigned*>(hds8q);

  const uintx4* wp = reinterpret_cast<const uintx4*>(wq) + (size_t)row * 16;
  const float  sc_r = sc[row];
  unsigned* hxb = hx + (size_t)b * 128;   // [par][64] dwords

  // own-column weight groups (loop-invariant; 16 VGPRs)
  const uintx4 wo0 = wp[4 * role + 0];
  const uintx4 wo1 = wp[4 * role + 1];
  const uintx4 wo2 = wp[4 * role + 2];
  const uintx4 wo3 = wp[4 * role + 3];

  for (int i = tid; i < TP2n; i += 448) {
    ev_s[i] = event[b * TP2n + i];
    dt_s[i] = dtime[b * TP2n + i];
  }
  if (tid < 64) hds8[tid] = 0u;
  if (tid == 0) hflag = 0;
  __syncthreads();

  float c_r = 0.f, cb_r = 0.f;          // unit state (threads 0..63)
  const int j_u = 64 * role + tid;      // this thread's unit (tid<64)
  float ew_pf = EW[(size_t)ev_s[0] * H7n + row];
  int aloc = 0;                         // local-column partial (h(0)=0)

  for (int t = 0; t < Tn; ++t) {
    float ewc = ew_pf;
    ew_pf = EW[(size_t)ev_s[t + 1] * H7n + row];  // next-step prefetch

    // ---- Phase A: REMOTE columns only (local partial carried in aloc) ----
    int a0 = 0, a1 = 0, a2 = 0, a3 = 0;
#pragma unroll
    for (int kk = 1; kk <= 3; ++kk) {
      const int rr = (role + kk) & 3;
#pragma unroll
      for (int g = 0; g < 4; ++g) {
        const int i = 4 * rr + g;
        uintx4 ww = wp[i];               // 16 int8 weights (cols 16i..16i+15)
        uintx4 hh = hds8q[i];            // uniform-address broadcast read
        a0 = sdot4f(ww[0], hh[0], a0);
        a1 = sdot4f(ww[1], hh[1], a1);
        a2 = sdot4f(ww[2], hh[2], a2);
        a3 = sdot4f(ww[3], hh[3], a3);
      }
    }
    zbuf[tid] = ewc + sc_r * (float)(((a0 + a1) + (a2 + a3)) + aloc);
    __syncthreads();

    const unsigned parQ = (unsigned)(t & 1);
    const unsigned tauQ = (unsigned)((t >> 1) & 1);

    // ---- Phase B (wave 0, boosted) + publish; concurrent remote poll ----
    if (tid < 64) {
      __builtin_amdgcn_s_setprio(1);
      float gi  = sigmf(zbuf[tid]);
      float gf  = sigmf(zbuf[64 + tid]);
      float go  = sigmf(zbuf[128 + tid]);
      float zc  = tanhfast(zbuf[192 + tid]);
      float gib = sigmf(zbuf[256 + tid]);
      float gfb = sigmf(zbuf[320 + tid]);
      float gd  = softplusf(zbuf[384 + tid]);
      float dt  = dt_s[t + 1];
      float ci  = gf * c_r + gi * zc;
      float cbi = gfb * cb_r + gib * zc;
      float cn  = cbi + (ci - cbi) * __expf(-gd * dt);
      float hn  = go * tanhfast(cn);
      c_r = cn; cb_r = cbi;
      // int8 h, packed 4 units/dword via wave-internal shuffles
      unsigned bq = (unsigned)((int)rintf(
                        fminf(fmaxf(hn * 127.f, -127.f), 127.f))) & 255u;
      unsigned u0 = __shfl(bq, 4 * (tid & 15));
      unsigned u1 = __shfl(bq, 4 * (tid & 15) + 1);
      unsigned u2 = __shfl(bq, 4 * (tid & 15) + 2);
      unsigned u3 = __shfl(bq, 4 * (tid & 15) + 3);
      unsigned d = u0 | (u1 << 8) | (u2 << 16) | (u3 << 24);
      if (tid < 16) {
        hds8[16 * role + tid] = d;       // own copy: full precision
        if (t < Tn - 1)
          __hip_atomic_store(hxb + parQ * 64 + 16 * role + tid,
                             (d & 0xFFFFFFFEu) | tauQ,
                             __ATOMIC_RELAXED, __HIP_MEMORY_SCOPE_AGENT);
      }
      __builtin_amdgcn_s_setprio(0);
      if (tid == 0 && t < Tn - 1)        // release: orders the hds8 writes
        __hip_atomic_store(&hflag, t + 1, __ATOMIC_RELEASE,
                           __HIP_MEMORY_SCOPE_WORKGROUP);
      f16x2 p0; p0[0] = (_Float16)ci; p0[1] = (_Float16)cbi;
      f16x2 p1; p1[0] = (_Float16)gd; p1[1] = (_Float16)go;
      uint2 o;
      o.x = __builtin_bit_cast(unsigned, p0);
      o.y = __builtin_bit_cast(unsigned, p1);
      state[((size_t)b * Tn + t) * Hn + j_u] = o;
    } else if (tid < 112 && t < Tn - 1) {
      // wave 1 (48 lanes): poll the 3 remote roles' 16 dwords each
      int k  = tid - 64;                       // 0..47
      int rr = (role + 1 + (k >> 4)) & 3;      // the 3 other roles
      int m  = 16 * rr + (k & 15);
      unsigned v;
      do {
        v = __hip_atomic_load(hxb + parQ * 64 + m, __ATOMIC_RELAXED,
                              __HIP_MEMORY_SCOPE_AGENT);
      } while ((v & 1u) != tauQ);
      hds8[m] = v;                             // lsb-tag noise: 1/127 on 1 of 4
    }

    // ---- local-column partial for the NEXT step (overlaps the poll RT) ----
    if (t < Tn - 1) {
      while (__hip_atomic_load(&hflag, __ATOMIC_ACQUIRE,
                               __HIP_MEMORY_SCOPE_WORKGROUP) <= t) {}
      uintx4 h0 = hds8q[4 * role + 0];
      uintx4 h1 = hds8q[4 * role + 1];
      uintx4 h2 = hds8q[4 * role + 2];
      uintx4 h3 = hds8q[4 * role + 3];
      int l0 = 0, l1 = 0, l2 = 0, l3 = 0;
      l0 = sdot4f(wo0[0], h0[0], l0); l1 = sdot4f(wo0[1], h0[1], l1);
      l2 = sdot4f(wo0[2], h0[2], l2); l3 = sdot4f(wo0[3], h0[3], l3);
      l0 = sdot4f(wo1[0], h1[0], l0); l1 = sdot4f(wo1[1], h1[1], l1);
      l2 = sdot4f(wo1[2], h1[2], l2); l3 = sdot4f(wo1[3], h1[3], l3);
      l0 = sdot4f(wo2[0], h2[0], l0); l1 = sdot4f(wo2[1], h2[1], l1);
      l2 = sdot4f(wo2[2], h2[2], l2); l3 = sdot4f(wo2[3], h2[3], l3);
      l0 = sdot4f(wo3[0], h3[0], l0); l1 = sdot4f(wo3[1], h3[1], l1);
      l2 = sdot4f(wo3[2], h3[2], l2); l3 = sdot4f(wo3[3], h3[3], l3);
      aloc = (l0 + l1) + (l2 + l3);
    }
    __syncthreads();
  }
}

// ---------------------------------------------------------------------------
// log_lam_tgt: grid (16, 64) — block = (64 t's, one b), 4 waves x 16 t each,
// LDS partial-reduce, ONE atomic per block (round-16 proven: helper-kernel
// gap 620us -> 19us).
__global__ __launch_bounds__(256) void k_post(
    const uint2* __restrict__ state, const int* __restrict__ event,
    const float* __restrict__ dtime, const float* __restrict__ Wl,
    float* __restrict__ loglik_sum) {
  const int b = blockIdx.y;
  const int wave = threadIdx.x >> 6;
  const int lane = threadIdx.x & 63;
  __shared__ float part[4];
  float acc = 0.f;
  for (int i = 0; i < 16; ++i) {
    const int t = blockIdx.x * 64 + wave * 16 + i;
    if (t >= Tn) break;
    const int tgt = event[b * TP2n + t + 1];
    if (tgt >= Kn) continue;                   // wave-uniform
    const float dtv = dtime[b * TP2n + t + 1];
    const uint2* srow = state + ((size_t)b * Tn + t) * Hn;
    uint4 sA = *reinterpret_cast<const uint4*>(srow + lane * 4);
    uint4 sB = *reinterpret_cast<const uint4*>(srow + lane * 4 + 2);
    float4 wl = *reinterpret_cast<const float4*>(Wl + tgt * Hn + lane * 4);
    float h[4];
#pragma unroll
    for (int qq = 0; qq < 4; ++qq) {
      unsigned lo = (qq == 0) ? sA.x : (qq == 1) ? sA.z : (qq == 2) ? sB.x : sB.z;
      unsigned hi = (qq == 0) ? sA.y : (qq == 1) ? sA.w : (qq == 2) ? sB.y : sB.w;
      f16x2 p0 = u2h(lo), p1 = u2h(hi);
      float c = p0[0], cb = p0[1], gd = p1[0], go = p1[1];
      float cs = cb + (c - cb) * __expf(-gd * dtv);
      h[qq] = go * tanhfast(cs);
    }
    float d = h[0] * wl.x + h[1] * wl.y + h[2] * wl.z + h[3] * wl.w;
#pragma unroll
    for (int off = 32; off; off >>= 1) d += __shfl_down(d, off);
    if (lane == 0) acc += __logf(softplusf(d) + EPSF);
  }
  if (lane == 0) part[wave] = acc;
  __syncthreads();
  if (threadIdx.x == 0)
    atomicAdd(&loglik_sum[b], part[0] + part[1] + part[2] + part[3]);
}

// ---------------------------------------------------------------------------
// Sampling: 1024 blocks (16/batch, 64 samples each) x 128 threads.
// Wl int8 TRANSPOSED in LDS (32KB, loaded once/block). Per sample: gather
// state, hy int8 packed via pair-shuffles into LDS, then 16 contiguous b128
// LDS reads + 64 sdot4 per thread (thread = Wl row).
__global__ __launch_bounds__(128) void k_samp(
    const uint2* __restrict__ state, const unsigned* __restrict__ wlq,
    const float* __restrict__ scl,
    const int* __restrict__ sidx, const float* __restrict__ sdt,
    const float* __restrict__ smask,
    float* __restrict__ lam_acc, float* __restrict__ mask_acc) {
  const int blk = blockIdx.x;
  const int b = blk >> 4;
  const int base = (b << 10) + (blk & 15) * 64;
  const int tid = threadIdx.x;

  __shared__ uintx4 wlt4[2048];   // 32KB: [kg 0..15][row 0..127]
  __shared__ uintx4 hq4[16];      // 256 int8 hy, unit-major 4/dword
  __shared__ float  red[2];

  const uintx4* wg = reinterpret_cast<const uintx4*>(wlq);
  for (int i = tid; i < 2048; i += 128) wlt4[i] = wg[i];
  const float sc_row = scl[tid];
  float accl = 0.f, accm = 0.f;

  int   row = sidx[base];
  float dtv = sdt[base];
  float mk  = smask[base];
  uint4 st = *reinterpret_cast<const uint4*>(state + (size_t)row * Hn + 2 * tid);
  __syncthreads();

  for (int s = 0; s < 64; ++s) {
    // hy int8 for units 2*tid, 2*tid+1
    f16x2 p0 = u2h(st.x), p1 = u2h(st.y);
    f16x2 q0 = u2h(st.z), q1 = u2h(st.w);
    float cs0 = (float)p0[1] + ((float)p0[0] - (float)p0[1]) * __expf(-(float)p1[0] * dtv);
    float cs1 = (float)q0[1] + ((float)q0[0] - (float)q0[1]) * __expf(-(float)q1[0] * dtv);
    float h0 = (float)p1[1] * tanhfast(cs0);
    float h1 = (float)q1[1] * tanhfast(cs1);
    unsigned i0 = (unsigned)((int)rintf(fminf(fmaxf(h0 * 127.f, -127.f), 127.f))) & 255u;
    unsigned i1 = (unsigned)((int)rintf(fminf(fmaxf(h1 * 127.f, -127.f), 127.f))) & 255u;
    unsigned p = i0 | (i1 << 8);
    unsigned pn = __shfl(p, tid + 1);          // wave-local: (tid+1)&63
    if (!(tid & 1))
      reinterpret_cast<unsigned*>(hq4)[tid >> 1] = p | (pn << 16);

    // prefetch next sample's state row
    uint4 st_n = st; float dt_n = dtv, mk_n = mk;
    if (s < 63) {
      int sg = base + s + 1;
      int r2 = sidx[sg];
      dt_n = sdt[sg];
      mk_n = smask[sg];
      st_n = *reinterpret_cast<const uint4*>(state + (size_t)r2 * Hn + 2 * tid);
    }
    __syncthreads();

    int acc = 0;
#pragma unroll
    for (int kg = 0; kg < 16; ++kg) {
      uintx4 w4 = wlt4[kg * 128 + tid];        // contiguous b128, no conflict
      uintx4 h4 = hq4[kg];                     // uniform broadcast
      acc = sdot4f(w4[0], h4[0], acc);
      acc = sdot4f(w4[1], h4[1], acc);
      acc = sdot4f(w4[2], h4[2], acc);
      acc = sdot4f(w4[3], h4[3], acc);
    }
    float lam = softplusf(sc_row * (float)acc);
#pragma unroll
    for (int off = 32; off; off >>= 1) lam += __shfl_down(lam, off);
    if ((tid & 63) == 0) red[tid >> 6] = lam;
    __syncthreads();
    if (tid == 0) {
      accl += (red[0] + red[1]) * mk;
      accm += mk;
    }
    st = st_n; dtv = dt_n; mk = mk_n;
  }
  if (tid == 0) {
    atomicAdd(&lam_acc[b], accl);
    atomicAdd(&mask_acc[b], accm);
  }
}

// ---------------------------------------------------------------------------
__global__ void k_final(const float* __restrict__ loglik_sum,
                        const float* __restrict__ lam_acc,
                        const float* __restrict__ mask_acc,
                        const float* __restrict__ duration,
                        float* __restrict__ out) {
  int b = threadIdx.x;
  if (b < Bn) out[b] = loglik_sum[b] - (lam_acc[b] / mask_acc[b]) * duration[b];
}

// ---------------------------------------------------------------------------
extern "C" void kernel_launch(void* const* d_in, const int* in_sizes, int n_in,
                              void* d_out, int out_size, void* d_ws, size_t ws_size,
                              hipStream_t stream) {
  const int*   event    = (const int*)d_in[0];
  const float* dtime    = (const float*)d_in[1];
  const float* duration = (const float*)d_in[3];
  const float* sdt      = (const float*)d_in[4];
  const int*   sidx     = (const int*)d_in[5];
  const float* smask    = (const float*)d_in[6];
  const float* Emb      = (const float*)d_in[7];
  const float* W        = (const float*)d_in[8];
  const float* bv       = (const float*)d_in[9];
  const float* Wl       = (const float*)d_in[10];

  char* ws = (char*)d_ws;
  // layout: EWp(0.94MB)@0 | wq8(448KB)@1MB | acc(768B)@2MB | hx(32KB)@2MB+8KB
  //         | sc(7KB)@2MB+48KB | wlq(32KB)@2MB+128KB | scl(512B)@2MB+192KB
  //         | packed state(134MB)@4MB
  float*    EW         = (float*)(ws + 0);
  unsigned* wq         = (unsigned*)(ws + (1u << 20));
  float*    lam_acc    = (float*)(ws + (2u << 20));
  float*    mask_acc   = lam_acc + 64;
  float*    loglik_sum = lam_acc + 128;
  unsigned* hx         = (unsigned*)(ws + (2u << 20) + 8192);
  float*    sc         = (float*)(ws + (2u << 20) + 49152);
  unsigned* wlq        = (unsigned*)(ws + (2u << 20) + 131072);
  float*    scl        = (float*)(ws + (2u << 20) + 196608);
  uint2*    state      = (uint2*)(ws + (4u << 20));

  k_ew<<<dim3(NEn, 16), dim3(256), 0, stream>>>(Emb, W, bv, EW);
  k_wq8<<<dim3(H7n), dim3(64), 0, stream>>>(W, wq, sc);
  k_wlq<<<dim3(Kn), dim3(64), 0, stream>>>(Wl, wlq, scl);
  k_init<<<dim3(1), dim3(1024), 0, stream>>>(lam_acc, hx);
  k_scan<<<dim3(256), dim3(448), 0, stream>>>(event, dtime, EW, wq, sc, hx,
                                              state);
  k_post<<<dim3(16, 64), dim3(256), 0, stream>>>(state, event, dtime, Wl,
                                                 loglik_sum);
  k_samp<<<dim3(1024), dim3(128), 0, stream>>>(state, wlq, scl, sidx, sdt,
                                               smask, lam_acc, mask_acc);
  k_final<<<dim3(1), dim3(64), 0, stream>>>(loglik_sum, lam_acc, mask_acc,
                                            duration, (float*)d_out);
}

// Round 19
// 1966.366 us; speedup vs baseline: 1.0426x; 1.0426x over previous
//
#include <hip/hip_runtime.h>
#include <hip/hip_fp16.h>
#include <cstdint>
#include <cstddef>

#define EPSF 2.220446049250313e-16f

// Sizes (fixed by the problem)
#define Bn   64
#define TP2n 1024
#define Tn   1023
#define Hn   256
#define H7n  1792
#define Kn   128
#define NEn  131

typedef _Float16 f16x2 __attribute__((ext_vector_type(2)));
typedef unsigned uintx4 __attribute__((ext_vector_type(4)));

__device__ __forceinline__ f16x2 u2h(unsigned u) { return __builtin_bit_cast(f16x2, u); }
__device__ __forceinline__ f16x2 f2h(float f)    { return __builtin_bit_cast(f16x2, f); }

// 4-way signed-byte dot product with int32 accumulate (v_dot4_i32_i8).
__device__ __forceinline__ int sdot4f(unsigned a, unsigned b, int c) {
#if __has_builtin(__builtin_amdgcn_sdot4)
  return __builtin_amdgcn_sdot4((int)a, (int)b, c, false);
#else
  int r = c;
#pragma unroll
  for (int i = 0; i < 4; ++i) {
    int av = ((int)(a << (24 - 8 * i))) >> 24;
    int bv = ((int)(b << (24 - 8 * i))) >> 24;
    r += av * bv;
  }
  return r;
#endif
}

__device__ __forceinline__ float sigmf(float x) { return 1.f / (1.f + __expf(-x)); }

__device__ __forceinline__ float tanhfast(float x) {
  float t = __expf(2.f * fabsf(x));        // inf-safe: t=inf -> r=1
  float r = 1.f - 2.f / (t + 1.f);
  return copysignf(r, x);
}

__device__ __forceinline__ float softplusf(float x) {
  return fmaxf(x, 0.f) + log1pf(__expf(-fabsf(x)));
}

// Row permutation: r' = role*448 + g*64 + u  <->  orig r = g*256 + 64*role + u.
// Role r' block then owns ALL 7 gates of units [64*role, 64*role+64):
// Phase B is block-local; only h (256 int8) crosses blocks.
__device__ __host__ __forceinline__ int orig_row(int rp) {
  int role = rp / 448, i = rp % 448;
  return (i >> 6) * 256 + 64 * role + (i & 63);
}

// ---------------------------------------------------------------------------
// EWp[e][r'] = b[orig(r')] + sum_k Emb[e][k] * W[orig(r')][k]   (k<256)
// Wave-per-row: lane l reads W[r][4l..4l+3] (coalesced 1KB/row) + shuffle
// reduce.
__global__ __launch_bounds__(256) void k_ew(
    const float* __restrict__ Emb, const float* __restrict__ W,
    const float* __restrict__ bvec, float* __restrict__ EW) {
  const int e = blockIdx.x;      // 0..130
  const int chunk = blockIdx.y;  // 0..15
  const int tid = threadIdx.x;
  __shared__ float es[Hn];
  es[tid] = Emb[e * Hn + tid];
  __syncthreads();
  const int wv = tid >> 6, l = tid & 63;
  float4 ev = reinterpret_cast<const float4*>(es)[l];
  for (int i = 0; i < 28; ++i) {
    int rp = chunk * 112 + wv * 28 + i;
    int r = orig_row(rp);
    float4 wf = *reinterpret_cast<const float4*>(W + (size_t)r * 512 + 4 * l);
    float s = wf.x * ev.x + wf.y * ev.y + wf.z * ev.z + wf.w * ev.w;
#pragma unroll
    for (int off = 32; off; off >>= 1) s += __shfl_down(s, off);
    if (l == 0) EW[e * H7n + rp] = bvec[r] + s;
  }
}

// ---------------------------------------------------------------------------
// Quantize recurrent weights to int8 with per-row scale, PERMUTED rows.
// Dword j of row r' = bytes (k=4j..4j+3), natural order (matches sdot4 with
// h packed unit-major 4/dword). sc[r'] = max/127^2 (weight scale x h scale).
__global__ __launch_bounds__(64) void k_wq8(const float* __restrict__ W,
                                            unsigned* __restrict__ wq,
                                            float* __restrict__ sc) {
  const int rp = blockIdx.x;          // 0..1791 (permuted index)
  const int r  = orig_row(rp);
  const int j  = threadIdx.x;         // 0..63
  const float* wr = W + (size_t)r * 512 + 256;
  float4 wv = *reinterpret_cast<const float4*>(wr + 4 * j);
  float m = fmaxf(fmaxf(fabsf(wv.x), fabsf(wv.y)),
                  fmaxf(fabsf(wv.z), fabsf(wv.w)));
#pragma unroll
  for (int off = 32; off; off >>= 1) m = fmaxf(m, __shfl_xor(m, off));
  float inv = (m > 0.f) ? 127.f / m : 0.f;
  float v[4] = {wv.x, wv.y, wv.z, wv.w};
  unsigned d = 0;
#pragma unroll
  for (int q = 0; q < 4; ++q) {
    float s = fminf(fmaxf(v[q] * inv, -127.f), 127.f);
    unsigned byte = (unsigned)((int)rintf(s)) & 255u;
    d |= byte << (8 * q);
  }
  wq[(size_t)rp * 64 + j] = d;
  if (j == 0) sc[rp] = m / (127.f * 127.f);
}

// ---------------------------------------------------------------------------
// Quantize Wl to int8, TRANSPOSED for k_samp's LDS layout.
__global__ __launch_bounds__(64) void k_wlq(const float* __restrict__ Wl,
                                            unsigned* __restrict__ wlq,
                                            float* __restrict__ scl) {
  const int r = blockIdx.x;           // 0..127
  const int j = threadIdx.x;          // 0..63
  const float* row = Wl + (size_t)r * Hn;
  float4 v = reinterpret_cast<const float4*>(row)[j];
  float m = fmaxf(fmaxf(fabsf(v.x), fabsf(v.y)),
                  fmaxf(fabsf(v.z), fabsf(v.w)));
#pragma unroll
  for (int off = 32; off; off >>= 1) m = fmaxf(m, __shfl_xor(m, off));
  float inv = (m > 0.f) ? 127.f / m : 0.f;
  float vv[4] = {v.x, v.y, v.z, v.w};
  unsigned d = 0;
#pragma unroll
  for (int qi = 0; qi < 4; ++qi) {
    unsigned byte = (unsigned)((int)rintf(
        fminf(fmaxf(vv[qi] * inv, -127.f), 127.f))) & 255u;
    d |= byte << (8 * qi);
  }
  wlq[(((size_t)(j >> 2)) * 128 + r) * 4 + (j & 3)] = d;
  if (j == 0) scl[r] = m / (127.f * 127.f);
}

// ---------------------------------------------------------------------------
// Init accumulators and the h-exchange buffer. hx dwords get lsb=1: first
// expected tag is 0, so poison / stale replay data can never false-positive.
__global__ void k_init(float* __restrict__ acc, unsigned* __restrict__ hx) {
  int i = threadIdx.x;  // 1024 threads
  if (i < 192) acc[i] = 0.f;  // lam_acc[64], mask_acc[64], loglik_sum[64]
  for (int k = i; k < Bn * 128; k += 1024) hx[k] = 1u;
}

// ---------------------------------------------------------------------------
// Sequential CT-LSTM scan, 4 blocks/batch, 448 threads, 1 permuted row each
// — the ROUND-14/17 structure (best measured: 1.78us/step). The per-step
// cost is the agent-scope publish->fabric->poll round trip; rounds 9/13/15/
// 16/18 proved bytes, barrier count, LDS residency, and poll-overlap are all
// non-factors. int8 weights x int8 h via v_dot4_i32_i8; h published as 16
// tagged dwords/role (tag = dword lsb, parity double-buffer), polled by 48
// lanes of wave 1 concurrently with wave 0's gate math.
__global__ __launch_bounds__(448) void k_scan(
    const int* __restrict__ event, const float* __restrict__ dtime,
    const float* __restrict__ EW, const unsigned* __restrict__ wq,
    const float* __restrict__ sc, unsigned* __restrict__ hx,
    uint2* __restrict__ state) {
  const int x = blockIdx.x;
  // co-locate a batch's 4 blocks on one XCD (assumed xcd = blockIdx % 8);
  // correctness does not depend on this mapping.
  const int xcd = x & 7, q = x >> 3;
  const int b = xcd * 8 + (q >> 2);
  const int role = q & 3;
  const int tid = threadIdx.x;
  const int row = role * 448 + tid;     // permuted row index

  __shared__ float    zbuf[448];        // this block's z slice (local!)
  __shared__ uintx4   hds8q[16];        // 256 int8 h, unit-major 4/dword
  __shared__ int      ev_s[TP2n];
  __shared__ float    dt_s[TP2n];
  unsigned* hds8 = reinterpret_cast<unsigned*>(hds8q);

  const uintx4* wp = reinterpret_cast<const uintx4*>(wq) + (size_t)row * 16;
  const float  sc_r = sc[row];
  unsigned* hxb = hx + (size_t)b * 128;   // [par][64] dwords

  for (int i = tid; i < TP2n; i += 448) {
    ev_s[i] = event[b * TP2n + i];
    dt_s[i] = dtime[b * TP2n + i];
  }
  if (tid < 64) hds8[tid] = 0u;
  __syncthreads();

  float c_r = 0.f, cb_r = 0.f;          // unit state (threads 0..63)
  const int j_u = 64 * role + tid;      // this thread's unit (tid<64)
  float ew_pf = EW[(size_t)ev_s[0] * H7n + row];

  for (int t = 0; t < Tn; ++t) {
    float ewc = ew_pf;
    ew_pf = EW[(size_t)ev_s[t + 1] * H7n + row];  // next-step prefetch

    // ---- Phase A: z for this row (int8 weights x int8 h, sdot4) ----
    int acc0 = 0, acc1 = 0, acc2 = 0, acc3 = 0;
#pragma unroll
    for (int i = 0; i < 16; ++i) {
      uintx4 ww = wp[i];               // 16 int8 weights (cols 16i..16i+15)
      uintx4 hh = hds8q[i];            // uniform-address broadcast read
      acc0 = sdot4f(ww[0], hh[0], acc0);
      acc1 = sdot4f(ww[1], hh[1], acc1);
      acc2 = sdot4f(ww[2], hh[2], acc2);
      acc3 = sdot4f(ww[3], hh[3], acc3);
    }
    zbuf[tid] = ewc + sc_r * (float)((acc0 + acc1) + (acc2 + acc3));
    __syncthreads();

    const unsigned parQ = (unsigned)(t & 1);
    const unsigned tauQ = (unsigned)((t >> 1) & 1);

    // ---- Phase B (wave 0) + fused int8 pack/publish; concurrent poll ----
    if (tid < 64) {
      float gi  = sigmf(zbuf[tid]);
      float gf  = sigmf(zbuf[64 + tid]);
      float go  = sigmf(zbuf[128 + tid]);
      float zc  = tanhfast(zbuf[192 + tid]);
      float gib = sigmf(zbuf[256 + tid]);
      float gfb = sigmf(zbuf[320 + tid]);
      float gd  = softplusf(zbuf[384 + tid]);
      float dt  = dt_s[t + 1];
      float ci  = gf * c_r + gi * zc;
      float cbi = gfb * cb_r + gib * zc;
      float cn  = cbi + (ci - cbi) * __expf(-gd * dt);
      float hn  = go * tanhfast(cn);
      c_r = cn; cb_r = cbi;
      // int8 h, packed 4 units/dword via wave-internal shuffles
      unsigned bq = (unsigned)((int)rintf(
                        fminf(fmaxf(hn * 127.f, -127.f), 127.f))) & 255u;
      unsigned u0 = __shfl(bq, 4 * (tid & 15));
      unsigned u1 = __shfl(bq, 4 * (tid & 15) + 1);
      unsigned u2 = __shfl(bq, 4 * (tid & 15) + 2);
      unsigned u3 = __shfl(bq, 4 * (tid & 15) + 3);
      if (tid < 16) {
        unsigned d = u0 | (u1 << 8) | (u2 << 16) | (u3 << 24);
        hds8[16 * role + tid] = d;     // own copy: full precision
        if (t < Tn - 1)
          __hip_atomic_store(hxb + parQ * 64 + 16 * role + tid,
                             (d & 0xFFFFFFFEu) | tauQ,
                             __ATOMIC_RELAXED, __HIP_MEMORY_SCOPE_AGENT);
      }
      f16x2 p0; p0[0] = (_Float16)ci; p0[1] = (_Float16)cbi;
      f16x2 p1; p1[0] = (_Float16)gd; p1[1] = (_Float16)go;
      uint2 o;
      o.x = __builtin_bit_cast(unsigned, p0);
      o.y = __builtin_bit_cast(unsigned, p1);
      state[((size_t)b * Tn + t) * Hn + j_u] = o;
    } else if (tid < 112 && t < Tn - 1) {
      // wave 1 (48 lanes): poll the 3 remote roles' 16 dwords each
      int k  = tid - 64;                       // 0..47
      int rr = (role + 1 + (k >> 4)) & 3;      // the 3 other roles
      int m  = 16 * rr + (k & 15);
      unsigned v;
      do {
        v = __hip_atomic_load(hxb + parQ * 64 + m, __ATOMIC_RELAXED,
                              __HIP_MEMORY_SCOPE_AGENT);
      } while ((v & 1u) != tauQ);
      hds8[m] = v;                             // lsb-tag noise: 1/127 on 1 of 4
    }
    __syncthreads();
  }
}

// ---------------------------------------------------------------------------
// log_lam_tgt: grid (16, 64) — block = (64 t's, one b), 4 waves x 16 t each,
// LDS partial-reduce, ONE atomic per block (round-16 proven: helper-kernel
// gap 620us -> 19us).
__global__ __launch_bounds__(256) void k_post(
    const uint2* __restrict__ state, const int* __restrict__ event,
    const float* __restrict__ dtime, const float* __restrict__ Wl,
    float* __restrict__ loglik_sum) {
  const int b = blockIdx.y;
  const int wave = threadIdx.x >> 6;
  const int lane = threadIdx.x & 63;
  __shared__ float part[4];
  float acc = 0.f;
  for (int i = 0; i < 16; ++i) {
    const int t = blockIdx.x * 64 + wave * 16 + i;
    if (t >= Tn) break;
    const int tgt = event[b * TP2n + t + 1];
    if (tgt >= Kn) continue;                   // wave-uniform
    const float dtv = dtime[b * TP2n + t + 1];
    const uint2* srow = state + ((size_t)b * Tn + t) * Hn;
    uint4 sA = *reinterpret_cast<const uint4*>(srow + lane * 4);
    uint4 sB = *reinterpret_cast<const uint4*>(srow + lane * 4 + 2);
    float4 wl = *reinterpret_cast<const float4*>(Wl + tgt * Hn + lane * 4);
    float h[4];
#pragma unroll
    for (int qq = 0; qq < 4; ++qq) {
      unsigned lo = (qq == 0) ? sA.x : (qq == 1) ? sA.z : (qq == 2) ? sB.x : sB.z;
      unsigned hi = (qq == 0) ? sA.y : (qq == 1) ? sA.w : (qq == 2) ? sB.y : sB.w;
      f16x2 p0 = u2h(lo), p1 = u2h(hi);
      float c = p0[0], cb = p0[1], gd = p1[0], go = p1[1];
      float cs = cb + (c - cb) * __expf(-gd * dtv);
      h[qq] = go * tanhfast(cs);
    }
    float d = h[0] * wl.x + h[1] * wl.y + h[2] * wl.z + h[3] * wl.w;
#pragma unroll
    for (int off = 32; off; off >>= 1) d += __shfl_down(d, off);
    if (lane == 0) acc += __logf(softplusf(d) + EPSF);
  }
  if (lane == 0) part[wave] = acc;
  __syncthreads();
  if (threadIdx.x == 0)
    atomicAdd(&loglik_sum[b], part[0] + part[1] + part[2] + part[3]);
}

// ---------------------------------------------------------------------------
// Sampling: 1024 blocks (16/batch, 64 samples each) x 128 threads.
// Wl int8 TRANSPOSED in LDS (32KB, loaded once/block). Per sample: gather
// state, hy int8 packed via pair-shuffles into LDS, then 16 contiguous b128
// LDS reads + 64 sdot4 per thread (thread = Wl row).
__global__ __launch_bounds__(128) void k_samp(
    const uint2* __restrict__ state, const unsigned* __restrict__ wlq,
    const float* __restrict__ scl,
    const int* __restrict__ sidx, const float* __restrict__ sdt,
    const float* __restrict__ smask,
    float* __restrict__ lam_acc, float* __restrict__ mask_acc) {
  const int blk = blockIdx.x;
  const int b = blk >> 4;
  const int base = (b << 10) + (blk & 15) * 64;
  const int tid = threadIdx.x;

  __shared__ uintx4 wlt4[2048];   // 32KB: [kg 0..15][row 0..127]
  __shared__ uintx4 hq4[16];      // 256 int8 hy, unit-major 4/dword
  __shared__ float  red[2];

  const uintx4* wg = reinterpret_cast<const uintx4*>(wlq);
  for (int i = tid; i < 2048; i += 128) wlt4[i] = wg[i];
  const float sc_row = scl[tid];
  float accl = 0.f, accm = 0.f;

  int   row = sidx[base];
  float dtv = sdt[base];
  float mk  = smask[base];
  uint4 st = *reinterpret_cast<const uint4*>(state + (size_t)row * Hn + 2 * tid);
  __syncthreads();

  for (int s = 0; s < 64; ++s) {
    // hy int8 for units 2*tid, 2*tid+1
    f16x2 p0 = u2h(st.x), p1 = u2h(st.y);
    f16x2 q0 = u2h(st.z), q1 = u2h(st.w);
    float cs0 = (float)p0[1] + ((float)p0[0] - (float)p0[1]) * __expf(-(float)p1[0] * dtv);
    float cs1 = (float)q0[1] + ((float)q0[0] - (float)q0[1]) * __expf(-(float)q1[0] * dtv);
    float h0 = (float)p1[1] * tanhfast(cs0);
    float h1 = (float)q1[1] * tanhfast(cs1);
    unsigned i0 = (unsigned)((int)rintf(fminf(fmaxf(h0 * 127.f, -127.f), 127.f))) & 255u;
    unsigned i1 = (unsigned)((int)rintf(fminf(fmaxf(h1 * 127.f, -127.f), 127.f))) & 255u;
    unsigned p = i0 | (i1 << 8);
    unsigned pn = __shfl(p, tid + 1);          // wave-local: (tid+1)&63
    if (!(tid & 1))
      reinterpret_cast<unsigned*>(hq4)[tid >> 1] = p | (pn << 16);

    // prefetch next sample's state row
    uint4 st_n = st; float dt_n = dtv, mk_n = mk;
    if (s < 63) {
      int sg = base + s + 1;
      int r2 = sidx[sg];
      dt_n = sdt[sg];
      mk_n = smask[sg];
      st_n = *reinterpret_cast<const uint4*>(state + (size_t)r2 * Hn + 2 * tid);
    }
    __syncthreads();

    int acc = 0;
#pragma unroll
    for (int kg = 0; kg < 16; ++kg) {
      uintx4 w4 = wlt4[kg * 128 + tid];        // contiguous b128, no conflict
      uintx4 h4 = hq4[kg];                     // uniform broadcast
      acc = sdot4f(w4[0], h4[0], acc);
      acc = sdot4f(w4[1], h4[1], acc);
      acc = sdot4f(w4[2], h4[2], acc);
      acc = sdot4f(w4[3], h4[3], acc);
    }
    float lam = softplusf(sc_row * (float)acc);
#pragma unroll
    for (int off = 32; off; off >>= 1) lam += __shfl_down(lam, off);
    if ((tid & 63) == 0) red[tid >> 6] = lam;
    __syncthreads();
    if (tid == 0) {
      accl += (red[0] + red[1]) * mk;
      accm += mk;
    }
    st = st_n; dtv = dt_n; mk = mk_n;
  }
  if (tid == 0) {
    atomicAdd(&lam_acc[b], accl);
    atomicAdd(&mask_acc[b], accm);
  }
}

// ---------------------------------------------------------------------------
__global__ void k_final(const float* __restrict__ loglik_sum,
                        const float* __restrict__ lam_acc,
                        const float* __restrict__ mask_acc,
                        const float* __restrict__ duration,
                        float* __restrict__ out) {
  int b = threadIdx.x;
  if (b < Bn) out[b] = loglik_sum[b] - (lam_acc[b] / mask_acc[b]) * duration[b];
}

// ---------------------------------------------------------------------------
extern "C" void kernel_launch(void* const* d_in, const int* in_sizes, int n_in,
                              void* d_out, int out_size, void* d_ws, size_t ws_size,
                              hipStream_t stream) {
  const int*   event    = (const int*)d_in[0];
  const float* dtime    = (const float*)d_in[1];
  const float* duration = (const float*)d_in[3];
  const float* sdt      = (const float*)d_in[4];
  const int*   sidx     = (const int*)d_in[5];
  const float* smask    = (const float*)d_in[6];
  const float* Emb      = (const float*)d_in[7];
  const float* W        = (const float*)d_in[8];
  const float* bv       = (const float*)d_in[9];
  const float* Wl       = (const float*)d_in[10];

  char* ws = (char*)d_ws;
  // layout: EWp(0.94MB)@0 | wq8(448KB)@1MB | acc(768B)@2MB | hx(32KB)@2MB+8KB
  //         | sc(7KB)@2MB+48KB | wlq(32KB)@2MB+128KB | scl(512B)@2MB+192KB
  //         | packed state(134MB)@4MB
  float*    EW         = (float*)(ws + 0);
  unsigned* wq         = (unsigned*)(ws + (1u << 20));
  float*    lam_acc    = (float*)(ws + (2u << 20));
  float*    mask_acc   = lam_acc + 64;
  float*    loglik_sum = lam_acc + 128;
  unsigned* hx         = (unsigned*)(ws + (2u << 20) + 8192);
  float*    sc         = (float*)(ws + (2u << 20) + 49152);
  unsigned* wlq        = (unsigned*)(ws + (2u << 20) + 131072);
  float*    scl        = (float*)(ws + (2u << 20) + 196608);
  uint2*    state      = (uint2*)(ws + (4u << 20));

  k_ew<<<dim3(NEn, 16), dim3(256), 0, stream>>>(Emb, W, bv, EW);
  k_wq8<<<dim3(H7n), dim3(64), 0, stream>>>(W, wq, sc);
  k_wlq<<<dim3(Kn), dim3(64), 0, stream>>>(Wl, wlq, scl);
  k_init<<<dim3(1), dim3(1024), 0, stream>>>(lam_acc, hx);
  k_scan<<<dim3(256), dim3(448), 0, stream>>>(event, dtime, EW, wq, sc, hx,
                                              state);
  k_post<<<dim3(16, 64), dim3(256), 0, stream>>>(state, event, dtime, Wl,
                                                 loglik_sum);
  k_samp<<<dim3(1024), dim3(128), 0, stream>>>(state, wlq, scl, sidx, sdt,
                                               smask, lam_acc, mask_acc);
  k_final<<<dim3(1), dim3(64), 0, stream>>>(loglik_sum, lam_acc, mask_acc,
                                            duration, (float*)d_out);
}